// Round 11
// baseline (89.134 us; speedup 1.0000x reference)
//
#include <hip/hip_runtime.h>
#include <stdint.h>

#define KCODES  1024
#define CDIM    64
#define SPATIAL 32768
#define NPOS    65536
#define NEL     4194304

// d_out layout (floats), outputs concatenated in reference return order
#define OUT_Q    0
#define OUT_LOSS 4194304
#define OUT_IDX  4194305
#define OUT_SUM  4259841
#define OUT_EMB  4260097

// ws: 32 sets x 8KB {Ah0,Al0,Ah1,Al1,Ah2,Al2,Ah3,Al3} (1KB chunks, lane-linear),
// then eiExp[32][2][16] f32 at EIEXP: per-lane C-init vectors (-0.5*||e||^2)
#define NSET  32
#define SETB  8192
#define EIEXP 262144
#define BPOS  128
#define NRND  16           // rounds per wave (K-split 2: 16 sets each)

typedef _Float16 half8  __attribute__((ext_vector_type(8)));
typedef float    f32x4  __attribute__((ext_vector_type(4)));
typedef float    f32x16 __attribute__((ext_vector_type(16)));

// ---- prep: fragment-swizzle codebook (32x32x16 A-frags), eiExp, zero, passthrough ----
__global__ void prep_emb(const float* __restrict__ emb, char* __restrict__ ws,
                         float* __restrict__ out) {
    int gt = blockIdx.x * 256 + threadIdx.x;        // 64 blocks -> 0..16383
    if (gt == 0) out[OUT_LOSS] = 0.f;
    if (gt < 256) out[OUT_SUM + gt] = 0.f;
    {   // embedding passthrough (OUT_EMB odd offset -> scalar stores)
        float4 v = *(const float4*)(emb + (size_t)gt * 4);
        float* o = out + OUT_EMB + (size_t)gt * 4;
        o[0] = v.x; o[1] = v.y; o[2] = v.z; o[3] = v.w;
    }
    if (gt < 8192) {                                 // one (code, 8-ch octet) each
        int k = gt >> 3, oct = gt & 7;
        int set = k >> 5, row = k & 31;
        int ks = oct >> 1, hc = oct & 1;             // c = ks*16 + hc*8 + i
        const float* e = emb + (size_t)k * CDIM + oct * 8;
        char* rec = ws + (size_t)set * SETB;
        // A-frag: lane l = hc*32+row holds 8 fp16 at chunk(ks,hi/lo) + l*16
        _Float16* hi = (_Float16*)(rec + (ks * 2 + 0) * 1024 + (hc * 32 + row) * 16);
        _Float16* lo = (_Float16*)(rec + (ks * 2 + 1) * 1024 + (hc * 32 + row) * 16);
        float s2 = 0.f;
        half8 hv, lv;
#pragma unroll
        for (int i = 0; i < 8; ++i) {
            float v = e[i];
            s2 = fmaf(v, v, s2);
            _Float16 h = (_Float16)v;
            hv[i] = h;
            lv[i] = (_Float16)(v - (float)h);
        }
        *(half8*)hi = hv;
        *(half8*)lo = lv;
        s2 += __shfl_xor(s2, 1);                     // reduce over the octet group
        s2 += __shfl_xor(s2, 2);
        s2 += __shfl_xor(s2, 4);
        if (oct == 0) {
            // C/D row = (q&3) + 8*(q>>2) + 4h  ->  h = bit2(row), q = (row&3)|((row>>3)<<2)
            int hh = (row >> 2) & 1;
            int q  = (row & 3) | ((row >> 3) << 2);
            ((float*)(ws + EIEXP))[(set * 2 + hh) * 16 + q] = -0.5f * s2;
        }
    }
}

// async global->LDS, 16B per lane
#define GLDS16(GSRC, LDST)                                                     \
    __builtin_amdgcn_global_load_lds(                                          \
        (const __attribute__((address_space(1))) void*)(GSRC),                 \
        (__attribute__((address_space(3))) void*)(LDST), 16, 0, 0)

// ---- main VQ kernel ----
// Grid 512 x 512 thr (8 waves) = 2 blocks/CU = 4 waves/SIMD. Block owns 128
// positions. Wave (pg,kh): pg=wv&3 owns 32 positions, kh=wv>>2 scans half the
// codebook (16 sets of 32 codes). Two staging streams, each a 3-slot LDS ring
// staged 2 rounds ahead via global_load_lds, counted vmcnt(2) per wave.
// THIS ROUND: 3 independent MFMA chains per set (hh/hl/lh) x 4 waves/SIMD
// -> 12 concurrent MFMA streams per SIMD (chain-ILP x occupancy), plus
// s_setprio(1) around the MFMA cluster (T5). Score = x.e - 0.5||e||^2.
__global__ __launch_bounds__(512, 4) void vq_kernel(
        const float* __restrict__ in, const float* __restrict__ emb,
        const char* __restrict__ wsA, float* __restrict__ out) {
    // ring[kh][slot] : 6 x 8KB = 48KB; xl (33KB) aliases onto it (dead after prologue)
    __shared__ __align__(16) char ring[6][SETB];
    __shared__ __align__(16) float eiL[NSET * 32];   // 4KB C-init vectors
    __shared__ float candS[2][BPOS];
    __shared__ int   candK[2][BPOS];
    __shared__ int   kwin[BPOS];
    __shared__ float lred[8];

    const int tid  = threadIdx.x;
    const int lane = tid & 63, wv = tid >> 6;        // 8 waves
    const int col  = lane & 31, h = lane >> 5;
    const int pg   = wv & 3, kh = wv >> 2;           // pos-group / K-half
    const int p0   = blockIdx.x * BPOS;
    const int b    = p0 >> 15;                       // 128-tile never straddles batch
    const int s0   = p0 & 32767;
    const float* xin = in + (size_t)b * (CDIM * SPATIAL) + s0;
    const float* eiG = (const float*)(wsA + EIEXP);

    // ---- prologue: x -> xl (aliased), B-frags, eiL, then ring pre-stage ----
    float* xl = (float*)&ring[0][0];                 // 64 x 129 floats = 33KB
    {
        int p = tid & 127, cq = tid >> 7;
#pragma unroll
        for (int j = 0; j < 16; ++j) {
            int c = cq * 16 + j;
            xl[c * 129 + p] = xin[(size_t)c * SPATIAL + p];
        }
    }
    eiL[tid] = eiG[tid];
    eiL[tid + 512] = eiG[tid + 512];
    __syncthreads();

    half8 bh[4], bl[4];                              // 32 pos x 64 ch hi/lo = 32 VGPR
    {
        int pp = pg * 32 + col;
#pragma unroll
        for (int ks = 0; ks < 4; ++ks)
#pragma unroll
            for (int j = 0; j < 8; ++j) {
                int c = ks * 16 + h * 8 + j;         // B k-local = h*8+j (matches A)
                float v = xl[c * 129 + pp];
                _Float16 hh = (_Float16)v;
                bh[ks][j] = hh;
                bl[ks][j] = (_Float16)(v - (float)hh);
            }
    }
    __syncthreads();                                 // xl reads done; ring may overwrite

    // pre-stage rounds 0,1 of own stream (wave stages its pg's 2KB quarter)
    char* sl0 = &ring[kh * 3 + 0][0];
    char* sl1 = &ring[kh * 3 + 1][0];
    char* sl2 = &ring[kh * 3 + 2][0];
#define STAGE2(RSET, DST) do {                                                 \
        const char* src_ = wsA + (size_t)(RSET) * SETB + pg * 2048 + lane * 16;\
        char* dst_ = (DST) + pg * 2048 + lane * 16;                            \
        GLDS16(src_, dst_);                                                    \
        GLDS16(src_ + 1024, dst_ + 1024);                                      \
    } while (0)
    STAGE2(kh * 16 + 0, sl0);
    STAGE2(kh * 16 + 1, sl1);
    asm volatile("s_waitcnt vmcnt(2)" ::: "memory"); // round-0 data drained
    __syncthreads();

    // ---- main loop: 16 rounds, stream-private 3-slot ring, stage 2 ahead ----
    f32x16 maxS;
    int    maxR[16];
#pragma unroll
    for (int q = 0; q < 16; ++q) { maxS[q] = -3.402823466e38f; maxR[q] = 0; }

#pragma unroll 1
    for (int r = 0; r < NRND; ++r) {
        STAGE2(kh * 16 + ((r + 2) & 15), sl2);       // wraps at tail: harmless re-stage
        const int setid = kh * 16 + r;
        f32x16 eiv = *(const f32x16*)&eiL[(setid * 2 + h) * 16];
        const char* ap = sl0 + (size_t)lane * 16;
        f32x16 aA, aB, aC;                           // 3 independent chains, 4-deep each
        {
            half8 ah0 = *(const half8*)(ap);
            half8 al0 = *(const half8*)(ap + 1024);
            half8 ah1 = *(const half8*)(ap + 2048);
            half8 al1 = *(const half8*)(ap + 3072);
            half8 ah2 = *(const half8*)(ap + 4096);
            half8 al2 = *(const half8*)(ap + 5120);
            half8 ah3 = *(const half8*)(ap + 6144);
            half8 al3 = *(const half8*)(ap + 7168);
#pragma unroll
            for (int q = 0; q < 16; ++q) { aB[q] = 0.f; aC[q] = 0.f; }
            __builtin_amdgcn_s_setprio(1);
            // chain B (hi x lo) first: no eiv (lgkm) dependency at head
            aB = __builtin_amdgcn_mfma_f32_32x32x16_f16(ah0, bl[0], aB, 0, 0, 0);
            aC = __builtin_amdgcn_mfma_f32_32x32x16_f16(al0, bh[0], aC, 0, 0, 0);
            aA = __builtin_amdgcn_mfma_f32_32x32x16_f16(ah0, bh[0], eiv, 0, 0, 0);
            aB = __builtin_amdgcn_mfma_f32_32x32x16_f16(ah1, bl[1], aB, 0, 0, 0);
            aC = __builtin_amdgcn_mfma_f32_32x32x16_f16(al1, bh[1], aC, 0, 0, 0);
            aA = __builtin_amdgcn_mfma_f32_32x32x16_f16(ah1, bh[1], aA, 0, 0, 0);
            aB = __builtin_amdgcn_mfma_f32_32x32x16_f16(ah2, bl[2], aB, 0, 0, 0);
            aC = __builtin_amdgcn_mfma_f32_32x32x16_f16(al2, bh[2], aC, 0, 0, 0);
            aA = __builtin_amdgcn_mfma_f32_32x32x16_f16(ah2, bh[2], aA, 0, 0, 0);
            aB = __builtin_amdgcn_mfma_f32_32x32x16_f16(ah3, bl[3], aB, 0, 0, 0);
            aC = __builtin_amdgcn_mfma_f32_32x32x16_f16(al3, bh[3], aC, 0, 0, 0);
            aA = __builtin_amdgcn_mfma_f32_32x32x16_f16(ah3, bh[3], aA, 0, 0, 0);
            __builtin_amdgcn_s_setprio(0);
        }
        // vectorized per-q-slot argmax: 16 independent states, no serial chain.
        // For fixed q, k grows with r -> strict > keeps smallest k.
#pragma unroll
        for (int q = 0; q < 16; ++q) {
            float sc = (aA[q] + aB[q]) + aC[q];
            if (sc > maxS[q]) { maxS[q] = sc; maxR[q] = setid; }
        }
        char* t0 = sl0; sl0 = sl1; sl1 = sl2; sl2 = t0;   // rotate ring
        asm volatile("s_waitcnt vmcnt(2)" ::: "memory");  // next round's set drained
        __syncthreads();
    }
#undef STAGE2

    // ---- per-lane lex fold over q-slots (score desc, k asc) ----
    float best = maxS[0];
    int   bk   = maxR[0] * 32 + 4 * h;
#pragma unroll
    for (int q = 1; q < 16; ++q) {
        float sc = maxS[q];
        int   kk = maxR[q] * 32 + 4 * h + (q & 3) + 8 * (q >> 2);
        if (sc > best || (sc == best && kk < bk)) { best = sc; bk = kk; }
    }
    // cross-h combine (same position, disjoint code rows)
    {
        float os = __shfl_xor(best, 32);
        int   ok = __shfl_xor(bk, 32);
        if (os > best || (os == best && ok < bk)) { best = os; bk = ok; }
    }
    if (h == 0) {
        candS[kh][pg * 32 + col] = best;
        candK[kh][pg * 32 + col] = bk;
    }
    __syncthreads();

    // ---- combine the two K-halves, write indices ----
    if (tid < BPOS) {
        float s0v = candS[0][tid], s1v = candS[1][tid];
        int   k0v = candK[0][tid], k1v = candK[1][tid];
        int sel = (s1v > s0v) || (s1v == s0v && k1v < k0v);
        int bkf = sel ? k1v : k0v;
        kwin[tid] = bkf;
        out[OUT_IDX + p0 + tid] = (float)bkf;
    }
    __syncthreads();

    // ---- epilogue: coalesced q stores, exact f32 x re-read (L2-hot), loss ----
    float lsum = 0.f;
    {
        int p = tid & 127, cq = tid >> 7;
        int kk = kwin[p];
        const float* eb = emb + (size_t)kk * CDIM;
        float* q = out + OUT_Q + (size_t)b * (CDIM * SPATIAL) + s0;
#pragma unroll
        for (int j = 0; j < 16; ++j) {
            int c = cq * 16 + j;
            float x = xin[(size_t)c * SPATIAL + p];
            float e = eb[c];
            float d = e - x;                         // stop_grad(q - x)
            lsum = fmaf(d, d, lsum);
            q[(size_t)c * SPATIAL + p] = x + d;      // straight-through
        }
    }
#pragma unroll
    for (int off = 32; off > 0; off >>= 1) lsum += __shfl_down(lsum, off);
    if (lane == 0) lred[wv] = lsum;
    __syncthreads();
    if (tid == 0) {
        float t = 0.f;
#pragma unroll
        for (int w = 0; w < 8; ++w) t += lred[w];
        atomicAdd(out + OUT_LOSS, t * (0.25f / (float)NEL));
    }
}

extern "C" void kernel_launch(void* const* d_in, const int* in_sizes, int n_in,
                              void* d_out, int out_size, void* d_ws, size_t ws_size,
                              hipStream_t stream) {
    const float* in  = (const float*)d_in[0];   // [2,64,32,32,32] f32
    const float* emb = (const float*)d_in[1];   // [1024,64] f32
    float* out = (float*)d_out;
    char*  ws  = (char*)d_ws;                   // 266,240 B used

    prep_emb<<<64, 256, 0, stream>>>(emb, ws, out);
    vq_kernel<<<NPOS / BPOS, 512, 0, stream>>>(in, emb, ws, out);
}

// Round 12
// 54.002 us; speedup vs baseline: 1.6506x; 1.6506x over previous
//
#include <hip/hip_runtime.h>
#include <stdint.h>

#define KCODES  1024
#define CDIM    64
#define SPATIAL 32768
#define NPOS    65536
#define NEL     4194304

// d_out layout (floats), outputs concatenated in reference return order
#define OUT_Q    0
#define OUT_LOSS 4194304
#define OUT_IDX  4194305
#define OUT_SUM  4259841
#define OUT_EMB  4260097

// ws: 32 sets x 8KB {Ah0,Al0,Ah1,Al1,Ah2,Al2,Ah3,Al3} (1KB chunks, lane-linear),
// then eiExp[32][2][16] f32 at EIEXP: per-lane C-init vectors (-0.5*||e||^2)
#define NSET  32
#define SETB  8192
#define EIEXP 262144
#define BPOS  128
#define NRND  16           // rounds per wave (K-split 2: 16 sets each)

typedef _Float16 half8  __attribute__((ext_vector_type(8)));
typedef float    f32x4  __attribute__((ext_vector_type(4)));
typedef float    f32x16 __attribute__((ext_vector_type(16)));

// ---- prep: fragment-swizzle codebook (32x32x16 A-frags), eiExp, zero, passthrough ----
__global__ void prep_emb(const float* __restrict__ emb, char* __restrict__ ws,
                         float* __restrict__ out) {
    int gt = blockIdx.x * 256 + threadIdx.x;        // 64 blocks -> 0..16383
    if (gt == 0) out[OUT_LOSS] = 0.f;
    if (gt < 256) out[OUT_SUM + gt] = 0.f;
    {   // embedding passthrough (OUT_EMB odd offset -> scalar stores)
        float4 v = *(const float4*)(emb + (size_t)gt * 4);
        float* o = out + OUT_EMB + (size_t)gt * 4;
        o[0] = v.x; o[1] = v.y; o[2] = v.z; o[3] = v.w;
    }
    if (gt < 8192) {                                 // one (code, 8-ch octet) each
        int k = gt >> 3, oct = gt & 7;
        int set = k >> 5, row = k & 31;
        int ks = oct >> 1, hc = oct & 1;             // c = ks*16 + hc*8 + i
        const float* e = emb + (size_t)k * CDIM + oct * 8;
        char* rec = ws + (size_t)set * SETB;
        // A-frag: lane l = hc*32+row holds 8 fp16 at chunk(ks,hi/lo) + l*16
        _Float16* hi = (_Float16*)(rec + (ks * 2 + 0) * 1024 + (hc * 32 + row) * 16);
        _Float16* lo = (_Float16*)(rec + (ks * 2 + 1) * 1024 + (hc * 32 + row) * 16);
        float s2 = 0.f;
        half8 hv, lv;
#pragma unroll
        for (int i = 0; i < 8; ++i) {
            float v = e[i];
            s2 = fmaf(v, v, s2);
            _Float16 h = (_Float16)v;
            hv[i] = h;
            lv[i] = (_Float16)(v - (float)h);
        }
        *(half8*)hi = hv;
        *(half8*)lo = lv;
        s2 += __shfl_xor(s2, 1);                     // reduce over the octet group
        s2 += __shfl_xor(s2, 2);
        s2 += __shfl_xor(s2, 4);
        if (oct == 0) {
            // C/D row = (q&3) + 8*(q>>2) + 4h  ->  h = bit2(row), q = (row&3)|((row>>3)<<2)
            int hh = (row >> 2) & 1;
            int q  = (row & 3) | ((row >> 3) << 2);
            ((float*)(ws + EIEXP))[(set * 2 + hh) * 16 + q] = -0.5f * s2;
        }
    }
}

// async global->LDS, 16B per lane
#define GLDS16(GSRC, LDST)                                                     \
    __builtin_amdgcn_global_load_lds(                                          \
        (const __attribute__((address_space(1))) void*)(GSRC),                 \
        (__attribute__((address_space(3))) void*)(LDST), 16, 0, 0)

// ---- main VQ kernel ----
// Grid 512 x 512 thr (8 waves) = 2 blocks/CU = 4 waves/SIMD (LDS 56KB -> 2
// blocks; unified regs ~108 <= 128). Wave (pg,kh): pg=wv&3 owns 32 positions,
// kh=wv>>2 scans half the codebook (16 sets of 32 codes). Two staging streams,
// each a 3-slot LDS ring staged 2 rounds ahead via global_load_lds, counted
// vmcnt(2). 3 independent MFMA chains (hh/hl/lh) x 4 waves/SIMD = 12
// concurrent MFMA streams/SIMD; setprio(1) around the MFMA cluster (T5).
// NOTE: __launch_bounds__(512,4) empirically caps arch-VGPR at 64 and spills
// (R8/R11); (512,2) lets the ~108-reg working set allocate (R9-proven).
__global__ __launch_bounds__(512, 2) void vq_kernel(
        const float* __restrict__ in, const float* __restrict__ emb,
        const char* __restrict__ wsA, float* __restrict__ out) {
    // ring[kh][slot] : 6 x 8KB = 48KB; xl (33KB) aliases onto it (dead after prologue)
    __shared__ __align__(16) char ring[6][SETB];
    __shared__ __align__(16) float eiL[NSET * 32];   // 4KB C-init vectors
    __shared__ float candS[2][BPOS];
    __shared__ int   candK[2][BPOS];
    __shared__ int   kwin[BPOS];
    __shared__ float lred[8];

    const int tid  = threadIdx.x;
    const int lane = tid & 63, wv = tid >> 6;        // 8 waves
    const int col  = lane & 31, h = lane >> 5;
    const int pg   = wv & 3, kh = wv >> 2;           // pos-group / K-half
    const int p0   = blockIdx.x * BPOS;
    const int b    = p0 >> 15;                       // 128-tile never straddles batch
    const int s0   = p0 & 32767;
    const float* xin = in + (size_t)b * (CDIM * SPATIAL) + s0;
    const float* eiG = (const float*)(wsA + EIEXP);

    // ---- prologue: x -> xl (aliased), B-frags, eiL, then ring pre-stage ----
    float* xl = (float*)&ring[0][0];                 // 64 x 129 floats = 33KB
    {
        int p = tid & 127, cq = tid >> 7;
#pragma unroll
        for (int j = 0; j < 16; ++j) {
            int c = cq * 16 + j;
            xl[c * 129 + p] = xin[(size_t)c * SPATIAL + p];
        }
    }
    eiL[tid] = eiG[tid];
    eiL[tid + 512] = eiG[tid + 512];
    __syncthreads();

    half8 bh[4], bl[4];                              // 32 pos x 64 ch hi/lo = 32 VGPR
    {
        int pp = pg * 32 + col;
#pragma unroll
        for (int ks = 0; ks < 4; ++ks)
#pragma unroll
            for (int j = 0; j < 8; ++j) {
                int c = ks * 16 + h * 8 + j;         // B k-local = h*8+j (matches A)
                float v = xl[c * 129 + pp];
                _Float16 hh = (_Float16)v;
                bh[ks][j] = hh;
                bl[ks][j] = (_Float16)(v - (float)hh);
            }
    }
    __syncthreads();                                 // xl reads done; ring may overwrite

    // pre-stage rounds 0,1 of own stream (wave stages its pg's 2KB quarter)
    char* sl0 = &ring[kh * 3 + 0][0];
    char* sl1 = &ring[kh * 3 + 1][0];
    char* sl2 = &ring[kh * 3 + 2][0];
#define STAGE2(RSET, DST) do {                                                 \
        const char* src_ = wsA + (size_t)(RSET) * SETB + pg * 2048 + lane * 16;\
        char* dst_ = (DST) + pg * 2048 + lane * 16;                            \
        GLDS16(src_, dst_);                                                    \
        GLDS16(src_ + 1024, dst_ + 1024);                                      \
    } while (0)
    STAGE2(kh * 16 + 0, sl0);
    STAGE2(kh * 16 + 1, sl1);
    asm volatile("s_waitcnt vmcnt(2)" ::: "memory"); // round-0 data drained
    __syncthreads();

    // ---- main loop: 16 rounds, stream-private 3-slot ring, stage 2 ahead ----
    f32x16 maxS;
    int    maxR[16];
#pragma unroll
    for (int q = 0; q < 16; ++q) { maxS[q] = -3.402823466e38f; maxR[q] = 0; }

#pragma unroll 1
    for (int r = 0; r < NRND; ++r) {
        STAGE2(kh * 16 + ((r + 2) & 15), sl2);       // wraps at tail: harmless re-stage
        const int setid = kh * 16 + r;
        f32x16 eiv = *(const f32x16*)&eiL[(setid * 2 + h) * 16];
        const char* ap = sl0 + (size_t)lane * 16;
        f32x16 aA, aB, aC;                           // 3 independent chains, 4-deep each
        {
            half8 ah0 = *(const half8*)(ap);
            half8 al0 = *(const half8*)(ap + 1024);
            half8 ah1 = *(const half8*)(ap + 2048);
            half8 al1 = *(const half8*)(ap + 3072);
            half8 ah2 = *(const half8*)(ap + 4096);
            half8 al2 = *(const half8*)(ap + 5120);
            half8 ah3 = *(const half8*)(ap + 6144);
            half8 al3 = *(const half8*)(ap + 7168);
#pragma unroll
            for (int q = 0; q < 16; ++q) { aB[q] = 0.f; aC[q] = 0.f; }
            __builtin_amdgcn_s_setprio(1);
            // chain B (hi x lo) first: no eiv (lgkm) dependency at head
            aB = __builtin_amdgcn_mfma_f32_32x32x16_f16(ah0, bl[0], aB, 0, 0, 0);
            aC = __builtin_amdgcn_mfma_f32_32x32x16_f16(al0, bh[0], aC, 0, 0, 0);
            aA = __builtin_amdgcn_mfma_f32_32x32x16_f16(ah0, bh[0], eiv, 0, 0, 0);
            aB = __builtin_amdgcn_mfma_f32_32x32x16_f16(ah1, bl[1], aB, 0, 0, 0);
            aC = __builtin_amdgcn_mfma_f32_32x32x16_f16(al1, bh[1], aC, 0, 0, 0);
            aA = __builtin_amdgcn_mfma_f32_32x32x16_f16(ah1, bh[1], aA, 0, 0, 0);
            aB = __builtin_amdgcn_mfma_f32_32x32x16_f16(ah2, bl[2], aB, 0, 0, 0);
            aC = __builtin_amdgcn_mfma_f32_32x32x16_f16(al2, bh[2], aC, 0, 0, 0);
            aA = __builtin_amdgcn_mfma_f32_32x32x16_f16(ah2, bh[2], aA, 0, 0, 0);
            aB = __builtin_amdgcn_mfma_f32_32x32x16_f16(ah3, bl[3], aB, 0, 0, 0);
            aC = __builtin_amdgcn_mfma_f32_32x32x16_f16(al3, bh[3], aC, 0, 0, 0);
            aA = __builtin_amdgcn_mfma_f32_32x32x16_f16(ah3, bh[3], aA, 0, 0, 0);
            __builtin_amdgcn_s_setprio(0);
        }
        // vectorized per-q-slot argmax: 16 independent states, no serial chain.
        // For fixed q, k grows with r -> strict > keeps smallest k.
#pragma unroll
        for (int q = 0; q < 16; ++q) {
            float sc = (aA[q] + aB[q]) + aC[q];
            if (sc > maxS[q]) { maxS[q] = sc; maxR[q] = setid; }
        }
        char* t0 = sl0; sl0 = sl1; sl1 = sl2; sl2 = t0;   // rotate ring
        asm volatile("s_waitcnt vmcnt(2)" ::: "memory");  // next round's set drained
        __syncthreads();
    }
#undef STAGE2

    // ---- per-lane lex fold over q-slots (score desc, k asc) ----
    float best = maxS[0];
    int   bk   = maxR[0] * 32 + 4 * h;
#pragma unroll
    for (int q = 1; q < 16; ++q) {
        float sc = maxS[q];
        int   kk = maxR[q] * 32 + 4 * h + (q & 3) + 8 * (q >> 2);
        if (sc > best || (sc == best && kk < bk)) { best = sc; bk = kk; }
    }
    // cross-h combine (same position, disjoint code rows)
    {
        float os = __shfl_xor(best, 32);
        int   ok = __shfl_xor(bk, 32);
        if (os > best || (os == best && ok < bk)) { best = os; bk = ok; }
    }
    if (h == 0) {
        candS[kh][pg * 32 + col] = best;
        candK[kh][pg * 32 + col] = bk;
    }
    __syncthreads();

    // ---- combine the two K-halves, write indices ----
    if (tid < BPOS) {
        float s0v = candS[0][tid], s1v = candS[1][tid];
        int   k0v = candK[0][tid], k1v = candK[1][tid];
        int sel = (s1v > s0v) || (s1v == s0v && k1v < k0v);
        int bkf = sel ? k1v : k0v;
        kwin[tid] = bkf;
        out[OUT_IDX + p0 + tid] = (float)bkf;
    }
    __syncthreads();

    // ---- epilogue: coalesced q stores, exact f32 x re-read (L2-hot), loss ----
    float lsum = 0.f;
    {
        int p = tid & 127, cq = tid >> 7;
        int kk = kwin[p];
        const float* eb = emb + (size_t)kk * CDIM;
        float* q = out + OUT_Q + (size_t)b * (CDIM * SPATIAL) + s0;
#pragma unroll
        for (int j = 0; j < 16; ++j) {
            int c = cq * 16 + j;
            float x = xin[(size_t)c * SPATIAL + p];
            float e = eb[c];
            float d = e - x;                         // stop_grad(q - x)
            lsum = fmaf(d, d, lsum);
            q[(size_t)c * SPATIAL + p] = x + d;      // straight-through
        }
    }
#pragma unroll
    for (int off = 32; off > 0; off >>= 1) lsum += __shfl_down(lsum, off);
    if (lane == 0) lred[wv] = lsum;
    __syncthreads();
    if (tid == 0) {
        float t = 0.f;
#pragma unroll
        for (int w = 0; w < 8; ++w) t += lred[w];
        atomicAdd(out + OUT_LOSS, t * (0.25f / (float)NEL));
    }
}

extern "C" void kernel_launch(void* const* d_in, const int* in_sizes, int n_in,
                              void* d_out, int out_size, void* d_ws, size_t ws_size,
                              hipStream_t stream) {
    const float* in  = (const float*)d_in[0];   // [2,64,32,32,32] f32
    const float* emb = (const float*)d_in[1];   // [1024,64] f32
    float* out = (float*)d_out;
    char*  ws  = (char*)d_ws;                   // 266,240 B used

    prep_emb<<<64, 256, 0, stream>>>(emb, ws, out);
    vq_kernel<<<NPOS / BPOS, 512, 0, stream>>>(in, emb, ws, out);
}

// Round 13
// 44.933 us; speedup vs baseline: 1.9837x; 1.2018x over previous
//
#include <hip/hip_runtime.h>
#include <stdint.h>

#define KCODES  1024
#define CDIM    64
#define SPATIAL 32768
#define NPOS    65536
#define NEL     4194304

// d_out layout (floats), outputs concatenated in reference return order
#define OUT_Q    0
#define OUT_LOSS 4194304
#define OUT_IDX  4194305
#define OUT_SUM  4259841
#define OUT_EMB  4260097

// ws: 64 sets x 4KB {Ah0(ch0-31),Ah1(ch32-63),Al0,Al1} 1KB chunks (lane-linear
// 16x16x32 A-frags, 16 codes/set), then eiE[1024] f32 (-0.5||e||^2) at EIOFF
#define NSET16 64
#define SETB   4096
#define EIOFF  262144
#define BPOS   128

typedef _Float16 half8 __attribute__((ext_vector_type(8)));
typedef float    f32x4 __attribute__((ext_vector_type(4)));

// ---- prep: fragment-swizzle codebook into 16-code sets, ei, zero, passthrough ----
__global__ void prep_emb(const float* __restrict__ emb, char* __restrict__ ws,
                         float* __restrict__ out) {
    int gt = blockIdx.x * 256 + threadIdx.x;        // 64 blocks -> 0..16383
    if (gt == 0) out[OUT_LOSS] = 0.f;
    if (gt < 256) out[OUT_SUM + gt] = 0.f;
    {   // embedding passthrough (OUT_EMB odd offset -> scalar stores)
        float4 v = *(const float4*)(emb + (size_t)gt * 4);
        float* o = out + OUT_EMB + (size_t)gt * 4;
        o[0] = v.x; o[1] = v.y; o[2] = v.z; o[3] = v.w;
    }
    if (gt < 8192) {                                 // one (code, 8-ch octet) each
        int k = gt >> 3, oct = gt & 7;
        int set = k >> 4, row = k & 15;
        int s = oct >> 2, g = oct & 3;               // c = s*32 + g*8 + i
        const float* e = emb + (size_t)k * CDIM + oct * 8;
        char* rec = ws + (size_t)set * SETB;
        // A-frag (16x16x32): lane l = g*16+row holds 8 f16 at chunk + l*16
        _Float16* hi = (_Float16*)(rec + s * 1024 + ((g << 4) | row) * 16);
        _Float16* lo = (_Float16*)(rec + 2048 + s * 1024 + ((g << 4) | row) * 16);
        float s2 = 0.f;
        half8 hv, lv;
#pragma unroll
        for (int i = 0; i < 8; ++i) {
            float v = e[i];
            s2 = fmaf(v, v, s2);
            _Float16 h = (_Float16)v;
            hv[i] = h;
            lv[i] = (_Float16)(v - (float)h);
        }
        *(half8*)hi = hv;
        *(half8*)lo = lv;
        s2 += __shfl_xor(s2, 1);                     // reduce over the octet group
        s2 += __shfl_xor(s2, 2);
        s2 += __shfl_xor(s2, 4);
        // eiE layout [set][g][r] with row = g*4+r  ->  linear index == k
        if (oct == 0) ((float*)(ws + EIOFF))[k] = -0.5f * s2;
    }
}

// async global->LDS, 16B per lane (dst: lane0 base; HW adds lane*16)
#define GLDS16(GSRC, LDST)                                                     \
    __builtin_amdgcn_global_load_lds(                                          \
        (const __attribute__((address_space(1))) void*)(GSRC),                 \
        (__attribute__((address_space(3))) void*)(LDST), 16, 0, 0)

// ---- main VQ kernel ----
// Grid 512 x 512 thr (8 waves) = 2 blocks/CU = 4 waves/SIMD. Block owns 128
// positions. Wave (pg,kh): pg=wv&3 owns 32 positions (2 col-tiles of 16),
// kh=wv>>2 scans half the codebook: 32 sets of 16 codes via 16x16x32 f16 MFMA
// (fp16 2-way split, 3 terms = 12 MFMA/round as two independent 6-chains).
// Each wave PRIVATELY double-buffers its 4KB set ring via global_load_lds:
// ZERO barriers in the main loop, counted vmcnt(4) per wave (T4), full wave
// independence (R5) + async staging (R6) + 4 waves/SIMD (R10).
// Score = x.e - 0.5||e||^2 folded via MFMA C-init; argmax == argmin distance.
__global__ __launch_bounds__(512, 2) void vq_kernel(
        const float* __restrict__ in, const float* __restrict__ emb,
        const char* __restrict__ wsA, float* __restrict__ out) {
    // per-wave private ring [wave][slot][4KB] = 64KB; xl (33KB) aliases onto it
    __shared__ __align__(16) char ring[8][2][SETB];
    __shared__ __align__(16) float eiL[KCODES];      // 4KB (-0.5||e||^2, idx==k)
    __shared__ float candS[2][BPOS];
    __shared__ int   candK[2][BPOS];
    __shared__ int   kwin[BPOS];
    __shared__ float lred[8];

    const int tid  = threadIdx.x;
    const int lane = tid & 63, wv = tid >> 6;        // 8 waves
    const int col  = lane & 15, g = lane >> 4;       // C col / row-group
    const int pg   = wv & 3, kh = wv >> 2;           // pos-group / K-half
    const int p0   = blockIdx.x * BPOS;
    const int b    = p0 >> 15;                       // 128-tile never straddles batch
    const int s0   = p0 & 32767;
    const float* xin = in + (size_t)b * (CDIM * SPATIAL) + s0;

    // ---- prologue: x -> xl (aliased on ring), eiL copy ----
    float* xl = (float*)&ring[0][0][0];              // 64 x 129 f32 = 33KB
    {
        int p = tid & 127, cq = tid >> 7;
#pragma unroll
        for (int j = 0; j < 16; ++j) {
            int c = cq * 16 + j;
            xl[c * 129 + p] = xin[(size_t)c * SPATIAL + p];
        }
    }
    eiL[tid]       = ((const float*)(wsA + EIOFF))[tid];
    eiL[tid + 512] = ((const float*)(wsA + EIOFF))[tid + 512];
    __syncthreads();

    // ---- B-frags: 32 positions x 64 ch hi/lo = 32 VGPR (R2-verified layout:
    // lane: col=lane&15 (position), k-local = (lane>>4)*8 + j within 32-ch half s)
    half8 bh[2][2], bl[2][2];                        // [ntile][s]
#pragma unroll
    for (int nt = 0; nt < 2; ++nt)
#pragma unroll
        for (int s = 0; s < 2; ++s) {
            int pp = pg * 32 + nt * 16 + col;
#pragma unroll
            for (int j = 0; j < 8; ++j) {
                int c = s * 32 + g * 8 + j;
                float v = xl[c * 129 + pp];
                _Float16 hh = (_Float16)v;
                bh[nt][s][j] = hh;
                bl[nt][s][j] = (_Float16)(v - (float)hh);
            }
        }
    __syncthreads();                                 // xl dead; ring may overwrite

    // ---- main loop: 32 private rounds, 2-slot ring, zero barriers ----
    const char* myws = wsA + (size_t)kh * 32 * SETB; // this stream's 32 sets
    char* slotA = &ring[wv][0][0];
    char* slotB = &ring[wv][1][0];
#define STAGE4(RSET, DST) do {                                                 \
        const char* s_ = myws + (size_t)(RSET) * SETB + lane * 16;             \
        char* d_ = (DST) + lane * 16;                                          \
        GLDS16(s_,        d_);                                                 \
        GLDS16(s_ + 1024, d_ + 1024);                                          \
        GLDS16(s_ + 2048, d_ + 2048);                                          \
        GLDS16(s_ + 3072, d_ + 3072);                                          \
    } while (0)
    STAGE4(0, slotA);

    f32x4 maxS0, maxS1;                              // per-(ntile, r-slot) argmax state
    int   maxR0[4], maxR1[4];
#pragma unroll
    for (int r = 0; r < 4; ++r) {
        maxS0[r] = -3.402823466e38f; maxS1[r] = -3.402823466e38f;
        maxR0[r] = 0;                maxR1[r] = 0;
    }

#pragma unroll 1
    for (int r = 0; r < 32; ++r) {
        STAGE4((r + 1) & 31, slotB);                 // wraps at tail: harmless
        const int set = kh * 32 + r;                 // global set id, ascending in k
        asm volatile("s_waitcnt vmcnt(4)" ::: "memory");  // this round's 4 drained
        f32x4 eiv = *(const f32x4*)&eiL[set * 16 + g * 4];
        const char* ap = slotA + (size_t)lane * 16;
        half8 ah0 = *(const half8*)(ap);
        half8 ah1 = *(const half8*)(ap + 1024);
        half8 al0 = *(const half8*)(ap + 2048);
        half8 al1 = *(const half8*)(ap + 3072);
        // two independent 6-chains (one per position tile), ei as C-init
        f32x4 a0 = __builtin_amdgcn_mfma_f32_16x16x32_f16(ah0, bh[0][0], eiv, 0, 0, 0);
        f32x4 a1 = __builtin_amdgcn_mfma_f32_16x16x32_f16(ah0, bh[1][0], eiv, 0, 0, 0);
        a0 = __builtin_amdgcn_mfma_f32_16x16x32_f16(ah1, bh[0][1], a0, 0, 0, 0);
        a1 = __builtin_amdgcn_mfma_f32_16x16x32_f16(ah1, bh[1][1], a1, 0, 0, 0);
        a0 = __builtin_amdgcn_mfma_f32_16x16x32_f16(ah0, bl[0][0], a0, 0, 0, 0);
        a1 = __builtin_amdgcn_mfma_f32_16x16x32_f16(ah0, bl[1][0], a1, 0, 0, 0);
        a0 = __builtin_amdgcn_mfma_f32_16x16x32_f16(ah1, bl[0][1], a0, 0, 0, 0);
        a1 = __builtin_amdgcn_mfma_f32_16x16x32_f16(ah1, bl[1][1], a1, 0, 0, 0);
        a0 = __builtin_amdgcn_mfma_f32_16x16x32_f16(al0, bh[0][0], a0, 0, 0, 0);
        a1 = __builtin_amdgcn_mfma_f32_16x16x32_f16(al0, bh[1][0], a1, 0, 0, 0);
        a0 = __builtin_amdgcn_mfma_f32_16x16x32_f16(al1, bh[0][1], a0, 0, 0, 0);
        a1 = __builtin_amdgcn_mfma_f32_16x16x32_f16(al1, bh[1][1], a1, 0, 0, 0);
        // vectorized per-r-slot argmax; sets ascend -> strict > keeps smallest k
#pragma unroll
        for (int rr = 0; rr < 4; ++rr) {
            if (a0[rr] > maxS0[rr]) { maxS0[rr] = a0[rr]; maxR0[rr] = set; }
            if (a1[rr] > maxS1[rr]) { maxS1[rr] = a1[rr]; maxR1[rr] = set; }
        }
        char* t_ = slotA; slotA = slotB; slotB = t_; // swap ring
    }
#undef STAGE4

    // ---- per-lane lex fold (score desc, k asc), cross-g butterfly, publish ----
#pragma unroll
    for (int nt = 0; nt < 2; ++nt) {
        float bs = nt ? maxS1[0] : maxS0[0];
        int   bk = (nt ? maxR1[0] : maxR0[0]) * 16 + g * 4;
#pragma unroll
        for (int rr = 1; rr < 4; ++rr) {
            float sc = nt ? maxS1[rr] : maxS0[rr];
            int   kk = (nt ? maxR1[rr] : maxR0[rr]) * 16 + g * 4 + rr;
            if (sc > bs || (sc == bs && kk < bk)) { bs = sc; bk = kk; }
        }
        // combine the 4 row-groups (lanes col, col+16, col+32, col+48)
#pragma unroll
        for (int m = 16; m <= 32; m <<= 1) {
            float os = __shfl_xor(bs, m);
            int   ok = __shfl_xor(bk, m);
            if (os > bs || (os == bs && ok < bk)) { bs = os; bk = ok; }
        }
        if (g == 0) {
            candS[kh][pg * 32 + nt * 16 + col] = bs;
            candK[kh][pg * 32 + nt * 16 + col] = bk;
        }
    }
    __syncthreads();

    // ---- combine the two K-halves, write indices ----
    if (tid < BPOS) {
        float s0v = candS[0][tid], s1v = candS[1][tid];
        int   k0v = candK[0][tid], k1v = candK[1][tid];
        int sel = (s1v > s0v) || (s1v == s0v && k1v < k0v);
        int bkf = sel ? k1v : k0v;
        kwin[tid] = bkf;
        out[OUT_IDX + p0 + tid] = (float)bkf;
    }
    __syncthreads();

    // ---- epilogue: coalesced q stores, exact f32 x re-read (L2-hot), loss ----
    float lsum = 0.f;
    {
        int p = tid & 127, cq = tid >> 7;
        int kk = kwin[p];
        const float* eb = emb + (size_t)kk * CDIM;
        float* q = out + OUT_Q + (size_t)b * (CDIM * SPATIAL) + s0;
#pragma unroll
        for (int j = 0; j < 16; ++j) {
            int c = cq * 16 + j;
            float x = xin[(size_t)c * SPATIAL + p];
            float e = eb[c];
            float d = e - x;                         // stop_grad(q - x)
            lsum = fmaf(d, d, lsum);
            q[(size_t)c * SPATIAL + p] = x + d;      // straight-through
        }
    }
#pragma unroll
    for (int off = 32; off > 0; off >>= 1) lsum += __shfl_down(lsum, off);
    if (lane == 0) lred[wv] = lsum;
    __syncthreads();
    if (tid == 0) {
        float t = 0.f;
#pragma unroll
        for (int w = 0; w < 8; ++w) t += lred[w];
        atomicAdd(out + OUT_LOSS, t * (0.25f / (float)NEL));
    }
}

extern "C" void kernel_launch(void* const* d_in, const int* in_sizes, int n_in,
                              void* d_out, int out_size, void* d_ws, size_t ws_size,
                              hipStream_t stream) {
    const float* in  = (const float*)d_in[0];   // [2,64,32,32,32] f32
    const float* emb = (const float*)d_in[1];   // [1024,64] f32
    float* out = (float*)d_out;
    char*  ws  = (char*)d_ws;                   // 266,240 B used

    prep_emb<<<64, 256, 0, stream>>>(emb, ws, out);
    vq_kernel<<<NPOS / BPOS, 512, 0, stream>>>(in, emb, ws, out);
}